// Round 2
// baseline (393.345 us; speedup 1.0000x reference)
//
#include <hip/hip_runtime.h>
#include <hip/hip_bf16.h>

#define NFEAT 256
#define NQ    64          // NFEAT/4 float4 quads
#define CH    128         // rows per block chunk (balanced)
#define MAXB  129         // max segments + 1

// ---------------------------------------------------------------------------
// Kernel 0: offsets[B+1], block-assignment prefix bs[B+1], total block count.
// Segment s owns blocks [bs[s], bs[s+1]), each covering CH rows (last ragged).
// ---------------------------------------------------------------------------
__global__ void k_setup(const int* __restrict__ lengths, int B,
                        int* __restrict__ off, int* __restrict__ bs,
                        int* __restrict__ nblk) {
    if (threadIdx.x == 0) {
        int acc = 0, bacc = 0;
        for (int i = 0; i < B; ++i) {
            off[i] = acc; bs[i] = bacc;
            int L = lengths[i];
            acc += L; bacc += (L + CH - 1) / CH;
        }
        off[B] = acc; bs[B] = bacc; *nblk = bacc;
    }
}

// seg lookup: block bid belongs to segment s iff bs[s] <= bid < bs[s+1].
// 128 threads each test one range; winner writes LDS. O(1) per block.
__device__ __forceinline__ int find_seg(const int* __restrict__ bs, int B,
                                        int bid, int* sseg) {
    const int t = threadIdx.x;
    if (t < B) {
        int lo = bs[t], hi = bs[t + 1];
        if (lo <= bid && bid < hi) *sseg = t;
    }
    __syncthreads();
    return *sseg;
}

// ---------------------------------------------------------------------------
// Kernel 1: per-block partial sum / sum-of-squares per feature (balanced).
// Block = 256 threads = 4 row-lanes x 64 feature-quads (float4 each).
// ---------------------------------------------------------------------------
__global__ __launch_bounds__(256) void k_partial(const float* __restrict__ x,
                                                 const int* __restrict__ off,
                                                 const int* __restrict__ bs,
                                                 const int* __restrict__ nblk,
                                                 int B,
                                                 float* __restrict__ psum,
                                                 float* __restrict__ psumsq) {
    const int bid = blockIdx.x;
    if (bid >= *nblk) return;

    __shared__ int sseg;
    const int seg = find_seg(bs, B, bid, &sseg);
    const int r0 = off[seg] + (bid - bs[seg]) * CH;
    const int r1 = min(r0 + CH, off[seg + 1]);

    const int rl = threadIdx.x >> 6;   // 0..3 row lane
    const int q  = threadIdx.x & 63;   // feature quad

    float4 sum = make_float4(0.f, 0.f, 0.f, 0.f);
    float4 sq  = make_float4(0.f, 0.f, 0.f, 0.f);

    const float4* x4 = reinterpret_cast<const float4*>(x);
    for (int r = r0 + rl; r < r1; r += 4) {
        float4 v = x4[(size_t)r * NQ + q];
        sum.x += v.x; sum.y += v.y; sum.z += v.z; sum.w += v.w;
        sq.x  += v.x * v.x; sq.y += v.y * v.y; sq.z += v.z * v.z; sq.w += v.w * v.w;
    }

    __shared__ float4 lsum[4][NQ];
    __shared__ float4 lsq[4][NQ];
    lsum[rl][q] = sum;
    lsq[rl][q]  = sq;
    __syncthreads();

    if (rl == 0) {
        float4 a0 = lsum[0][q], a1 = lsum[1][q], a2 = lsum[2][q], a3 = lsum[3][q];
        float4 q0 = lsq[0][q],  q1 = lsq[1][q],  q2 = lsq[2][q],  q3 = lsq[3][q];
        float4 ts, tq;
        ts.x = a0.x + a1.x + a2.x + a3.x;
        ts.y = a0.y + a1.y + a2.y + a3.y;
        ts.z = a0.z + a1.z + a2.z + a3.z;
        ts.w = a0.w + a1.w + a2.w + a3.w;
        tq.x = q0.x + q1.x + q2.x + q3.x;
        tq.y = q0.y + q1.y + q2.y + q3.y;
        tq.z = q0.z + q1.z + q2.z + q3.z;
        tq.w = q0.w + q1.w + q2.w + q3.w;
        reinterpret_cast<float4*>(psum)[(size_t)bid * NQ + q]   = ts;
        reinterpret_cast<float4*>(psumsq)[(size_t)bid * NQ + q] = tq;
    }
}

// ---------------------------------------------------------------------------
// Kernel 2: reduce each segment's contiguous partial range -> mean, rstd.
// ---------------------------------------------------------------------------
__global__ __launch_bounds__(256) void k_finalize(const float* __restrict__ psum,
                                                  const float* __restrict__ psumsq,
                                                  const int* __restrict__ off,
                                                  const int* __restrict__ bs,
                                                  float* __restrict__ mean,
                                                  float* __restrict__ rstd) {
    const int seg = blockIdx.x;
    const int f   = threadIdx.x;
    const int b0 = bs[seg], b1 = bs[seg + 1];
    float s = 0.f, qq = 0.f;
    for (int b = b0; b < b1; ++b) {
        s  += psum[(size_t)b * NFEAT + f];
        qq += psumsq[(size_t)b * NFEAT + f];
    }
    const float cnt = (float)(off[seg + 1] - off[seg]);
    const float m = s / cnt;
    const float v = fmaxf(qq / cnt - m * m, 0.f);
    mean[(size_t)seg * NFEAT + f] = m;
    rstd[(size_t)seg * NFEAT + f] = rsqrtf(v + 1e-5f);
}

// ---------------------------------------------------------------------------
// Kernel 3: normalize (balanced blocks). Per-thread scale/shift in registers;
// inner loop = load float4, 4 FMA, store float4.
// ---------------------------------------------------------------------------
__global__ __launch_bounds__(256) void k_norm(const float* __restrict__ x,
                                              const int* __restrict__ off,
                                              const int* __restrict__ bs,
                                              const int* __restrict__ nblk,
                                              int B,
                                              const float* __restrict__ mean,
                                              const float* __restrict__ rstd,
                                              const float* __restrict__ weight,
                                              const float* __restrict__ bias,
                                              float* __restrict__ out) {
    const int bid = blockIdx.x;
    if (bid >= *nblk) return;

    __shared__ int sseg;
    const int seg = find_seg(bs, B, bid, &sseg);
    const int r0 = off[seg] + (bid - bs[seg]) * CH;
    const int r1 = min(r0 + CH, off[seg + 1]);

    const int rl = threadIdx.x >> 6;
    const int q  = threadIdx.x & 63;

    const float4 m  = reinterpret_cast<const float4*>(mean)[(size_t)seg * NQ + q];
    const float4 rs = reinterpret_cast<const float4*>(rstd)[(size_t)seg * NQ + q];
    const float4 w  = reinterpret_cast<const float4*>(weight)[q];
    const float4 b  = reinterpret_cast<const float4*>(bias)[q];

    float4 sc, sh;   // out = x*sc + sh
    sc.x = rs.x * w.x; sh.x = b.x - m.x * sc.x;
    sc.y = rs.y * w.y; sh.y = b.y - m.y * sc.y;
    sc.z = rs.z * w.z; sh.z = b.z - m.z * sc.z;
    sc.w = rs.w * w.w; sh.w = b.w - m.w * sc.w;

    const float4* x4 = reinterpret_cast<const float4*>(x);
    float4* o4 = reinterpret_cast<float4*>(out);
    for (int r = r0 + rl; r < r1; r += 4) {
        const size_t idx = (size_t)r * NQ + q;
        float4 v = x4[idx];
        float4 o;
        o.x = v.x * sc.x + sh.x;
        o.y = v.y * sc.y + sh.y;
        o.z = v.z * sc.z + sh.z;
        o.w = v.w * sc.w + sh.w;
        o4[idx] = o;
    }
}

extern "C" void kernel_launch(void* const* d_in, const int* in_sizes, int n_in,
                              void* d_out, int out_size, void* d_ws, size_t ws_size,
                              hipStream_t stream) {
    const float* x       = (const float*)d_in[0];
    const int*   lengths = (const int*)d_in[1];
    const float* weight  = (const float*)d_in[2];
    const float* bias    = (const float*)d_in[3];
    float*       out     = (float*)d_out;

    const int B = in_sizes[1];               // 128 segments
    const int N = in_sizes[0] / NFEAT;       // 524288 rows
    const int maxBlocks = N / CH + B;        // upper bound on assigned blocks

    // ws layout (16B-aligned chunks)
    char* ws = (char*)d_ws;
    int*   off    = (int*)ws;                                  // B+1 ints
    int*   bs     = off + MAXB + 7;                            // B+1 ints
    int*   nblk   = bs + MAXB + 7;                             // 1 int
    float* mean   = (float*)(ws + 4096);                       // B*F
    float* rstd   = mean + (size_t)B * NFEAT;                  // B*F
    float* psum   = rstd + (size_t)B * NFEAT;                  // maxBlocks*F
    float* psumsq = psum + (size_t)maxBlocks * NFEAT;          // maxBlocks*F

    k_setup<<<1, 64, 0, stream>>>(lengths, B, off, bs, nblk);
    k_partial<<<maxBlocks, 256, 0, stream>>>(x, off, bs, nblk, B, psum, psumsq);
    k_finalize<<<B, NFEAT, 0, stream>>>(psum, psumsq, off, bs, mean, rstd);
    k_norm<<<maxBlocks, 256, 0, stream>>>(x, off, bs, nblk, B, mean, rstd,
                                          weight, bias, out);
}